// Round 1
// baseline (2247.899 us; speedup 1.0000x reference)
//
#include <hip/hip_runtime.h>
#include <math.h>

#define NG 32
#define TPB 256

__device__ __forceinline__ float softplus_f(float x) {
    return (x > 0.f) ? (x + log1pf(expf(-x))) : log1pf(expf(x));
}

// ---------------- Pass 1: edge densities -> local_density[dst], rep -> e_graph ----------------
__global__ __launch_bounds__(TPB) void eam_pass1(
        const float* __restrict__ r,
        const int* __restrict__ dst,
        const int* __restrict__ n2g,
        const float* __restrict__ p_dens_amp,
        const float* __restrict__ p_dens_ls,
        const float* __restrict__ p_rep_amp,
        const float* __restrict__ p_rep_ls,
        float* __restrict__ local_density,
        float* __restrict__ e_graph,
        int E)
{
    __shared__ float sbin[NG];
    if (threadIdx.x < NG) sbin[threadIdx.x] = 0.f;
    __syncthreads();

    const float Ad = softplus_f(*p_dens_amp);
    const float Ld = softplus_f(*p_dens_ls);
    const float Ar = softplus_f(*p_rep_amp);
    const float Lr = softplus_f(*p_rep_ls);

    const float4* r4 = (const float4*)r;
    const int4*   d4 = (const int4*)dst;
    const int nquad  = E >> 2;
    const int stride = gridDim.x * blockDim.x;

    for (int q = blockIdx.x * blockDim.x + threadIdx.x; q < nquad; q += stride) {
        float4 a = r4[3*q + 0];
        float4 b = r4[3*q + 1];
        float4 c = r4[3*q + 2];
        int4  dd = d4[q];

        float bl0 = sqrtf(a.x*a.x + a.y*a.y + a.z*a.z);
        float bl1 = sqrtf(a.w*a.w + b.x*b.x + b.y*b.y);
        float bl2 = sqrtf(b.z*b.z + b.w*b.w + c.x*c.x);
        float bl3 = sqrtf(c.y*c.y + c.z*c.z + c.w*c.w);

        float dens0 = Ad * expf(-Ld * bl0);
        float dens1 = Ad * expf(-Ld * bl1);
        float dens2 = Ad * expf(-Ld * bl2);
        float dens3 = Ad * expf(-Ld * bl3);

        float rep0 = Ar * expf(-Lr * bl0);
        float rep1 = Ar * expf(-Lr * bl1);
        float rep2 = Ar * expf(-Lr * bl2);
        float rep3 = Ar * expf(-Lr * bl3);

        atomicAdd(&local_density[dd.x], dens0);
        atomicAdd(&local_density[dd.y], dens1);
        atomicAdd(&local_density[dd.z], dens2);
        atomicAdd(&local_density[dd.w], dens3);

        atomicAdd(&sbin[n2g[dd.x]], rep0);
        atomicAdd(&sbin[n2g[dd.y]], rep1);
        atomicAdd(&sbin[n2g[dd.z]], rep2);
        atomicAdd(&sbin[n2g[dd.w]], rep3);
    }

    // scalar tail (E not multiple of 4)
    for (int e = (nquad << 2) + blockIdx.x * blockDim.x + threadIdx.x; e < E; e += stride) {
        float x = r[3*e], y = r[3*e+1], z = r[3*e+2];
        float bl = sqrtf(x*x + y*y + z*z);
        int de = dst[e];
        atomicAdd(&local_density[de], Ad * expf(-Ld * bl));
        atomicAdd(&sbin[n2g[de]], Ar * expf(-Lr * bl));
    }

    __syncthreads();
    if (threadIdx.x < NG) atomicAdd(&e_graph[threadIdx.x], sbin[threadIdx.x]);
}

// ---------------- Pass 2: node embedding F -> e_graph; overwrite local_density with dF/d(ld) ----------------
__global__ __launch_bounds__(TPB) void eam_pass2(
        float* __restrict__ ld_g,          // in: local_density, out: g = dE/d(local_density)
        const int* __restrict__ n2g,
        const float* __restrict__ p_emb_amp,
        float* __restrict__ e_graph,
        int N)
{
    __shared__ float sbin[NG];
    if (threadIdx.x < NG) sbin[threadIdx.x] = 0.f;
    __syncthreads();

    const float Ae = softplus_f(*p_emb_amp);
    const int stride = gridDim.x * blockDim.x;

    for (int n = blockIdx.x * blockDim.x + threadIdx.x; n < N; n += stride) {
        float l = ld_g[n];
        float m = fmaxf(l, 1e-12f);
        float s = sqrtf(m);
        atomicAdd(&sbin[n2g[n]], -Ae * s);
        // d(-Ae*sqrt(max(l,eps)))/dl : max-clamp gates the gradient
        ld_g[n] = (l >= 1e-12f) ? (-0.5f * Ae / s) : 0.f;
    }

    __syncthreads();
    if (threadIdx.x < NG) atomicAdd(&e_graph[threadIdx.x], sbin[threadIdx.x]);
}

// ---------------- Pass 3: per-edge gradient -> scatter forces ----------------
__global__ __launch_bounds__(TPB) void eam_pass3(
        const float* __restrict__ r,
        const int* __restrict__ src,
        const int* __restrict__ dst,
        const float* __restrict__ g,       // dE/d(local_density) per node
        const float* __restrict__ p_dens_amp,
        const float* __restrict__ p_dens_ls,
        const float* __restrict__ p_rep_amp,
        const float* __restrict__ p_rep_ls,
        float* __restrict__ forces,
        int E)
{
    const float Ad = softplus_f(*p_dens_amp);
    const float Ld = softplus_f(*p_dens_ls);
    const float Ar = softplus_f(*p_rep_amp);
    const float Lr = softplus_f(*p_rep_ls);

    const float4* r4 = (const float4*)r;
    const int4*   d4 = (const int4*)dst;
    const int4*   s4 = (const int4*)src;
    const int nquad  = E >> 2;
    const int stride = gridDim.x * blockDim.x;

    for (int q = blockIdx.x * blockDim.x + threadIdx.x; q < nquad; q += stride) {
        float4 a = r4[3*q + 0];
        float4 b = r4[3*q + 1];
        float4 c = r4[3*q + 2];
        int4  dd = d4[q];
        int4  ss = s4[q];

        float x0 = a.x, y0 = a.y, z0 = a.z;
        float x1 = a.w, y1 = b.x, z1 = b.y;
        float x2 = b.z, y2 = b.w, z2 = c.x;
        float x3 = c.y, y3 = c.z, z3 = c.w;

        float bl0 = sqrtf(x0*x0 + y0*y0 + z0*z0);
        float bl1 = sqrtf(x1*x1 + y1*y1 + z1*z1);
        float bl2 = sqrtf(x2*x2 + y2*y2 + z2*z2);
        float bl3 = sqrtf(x3*x3 + y3*y3 + z3*z3);

        float dens0 = Ad * expf(-Ld * bl0), rep0 = Ar * expf(-Lr * bl0);
        float dens1 = Ad * expf(-Ld * bl1), rep1 = Ar * expf(-Lr * bl1);
        float dens2 = Ad * expf(-Ld * bl2), rep2 = Ar * expf(-Lr * bl2);
        float dens3 = Ad * expf(-Ld * bl3), rep3 = Ar * expf(-Lr * bl3);

        float dEdb0 = g[dd.x] * (-Ld * dens0) - Lr * rep0;
        float dEdb1 = g[dd.y] * (-Ld * dens1) - Lr * rep1;
        float dEdb2 = g[dd.z] * (-Ld * dens2) - Lr * rep2;
        float dEdb3 = g[dd.w] * (-Ld * dens3) - Lr * rep3;

        float s0 = (bl0 > 0.f) ? dEdb0 / bl0 : 0.f;
        float s1 = (bl1 > 0.f) ? dEdb1 / bl1 : 0.f;
        float s2 = (bl2 > 0.f) ? dEdb2 / bl2 : 0.f;
        float s3 = (bl3 > 0.f) ? dEdb3 / bl3 : 0.f;

        float fx0 = s0*x0, fy0 = s0*y0, fz0 = s0*z0;
        float fx1 = s1*x1, fy1 = s1*y1, fz1 = s1*z1;
        float fx2 = s2*x2, fy2 = s2*y2, fz2 = s2*z2;
        float fx3 = s3*x3, fy3 = s3*y3, fz3 = s3*z3;

        atomicAdd(&forces[3*dd.x+0], -fx0); atomicAdd(&forces[3*dd.x+1], -fy0); atomicAdd(&forces[3*dd.x+2], -fz0);
        atomicAdd(&forces[3*ss.x+0],  fx0); atomicAdd(&forces[3*ss.x+1],  fy0); atomicAdd(&forces[3*ss.x+2],  fz0);

        atomicAdd(&forces[3*dd.y+0], -fx1); atomicAdd(&forces[3*dd.y+1], -fy1); atomicAdd(&forces[3*dd.y+2], -fz1);
        atomicAdd(&forces[3*ss.y+0],  fx1); atomicAdd(&forces[3*ss.y+1],  fy1); atomicAdd(&forces[3*ss.y+2],  fz1);

        atomicAdd(&forces[3*dd.z+0], -fx2); atomicAdd(&forces[3*dd.z+1], -fy2); atomicAdd(&forces[3*dd.z+2], -fz2);
        atomicAdd(&forces[3*ss.z+0],  fx2); atomicAdd(&forces[3*ss.z+1],  fy2); atomicAdd(&forces[3*ss.z+2],  fz2);

        atomicAdd(&forces[3*dd.w+0], -fx3); atomicAdd(&forces[3*dd.w+1], -fy3); atomicAdd(&forces[3*dd.w+2], -fz3);
        atomicAdd(&forces[3*ss.w+0],  fx3); atomicAdd(&forces[3*ss.w+1],  fy3); atomicAdd(&forces[3*ss.w+2],  fz3);
    }

    // scalar tail
    for (int e = (nquad << 2) + blockIdx.x * blockDim.x + threadIdx.x; e < E; e += stride) {
        float x = r[3*e], y = r[3*e+1], z = r[3*e+2];
        float bl = sqrtf(x*x + y*y + z*z);
        int de = dst[e], se = src[e];
        float dens = Ad * expf(-Ld * bl), rep = Ar * expf(-Lr * bl);
        float dEdb = g[de] * (-Ld * dens) - Lr * rep;
        float s = (bl > 0.f) ? dEdb / bl : 0.f;
        float fx = s*x, fy = s*y, fz = s*z;
        atomicAdd(&forces[3*de+0], -fx); atomicAdd(&forces[3*de+1], -fy); atomicAdd(&forces[3*de+2], -fz);
        atomicAdd(&forces[3*se+0],  fx); atomicAdd(&forces[3*se+1],  fy); atomicAdd(&forces[3*se+2],  fz);
    }
}

extern "C" void kernel_launch(void* const* d_in, const int* in_sizes, int n_in,
                              void* d_out, int out_size, void* d_ws, size_t ws_size,
                              hipStream_t stream) {
    const float* r   = (const float*)d_in[0];
    const int*   src = (const int*)d_in[1];
    const int*   dst = (const int*)d_in[2];
    const int*   n2g = (const int*)d_in[3];
    const float* p_da = (const float*)d_in[4];
    const float* p_dl = (const float*)d_in[5];
    const float* p_ra = (const float*)d_in[6];
    const float* p_rl = (const float*)d_in[7];
    const float* p_ea = (const float*)d_in[8];

    const int E = in_sizes[1];   // 6,400,000
    const int N = in_sizes[3];   // 100,000

    float* e_graph = (float*)d_out;          // [NG]
    float* forces  = (float*)d_out + NG;     // [N*3]
    float* ld_g    = (float*)d_ws;           // [N]: local_density, then overwritten with g

    // zero outputs + density accumulator (harness poisons once; we must re-init each call)
    hipMemsetAsync(d_out, 0, (size_t)out_size * sizeof(float), stream);
    hipMemsetAsync(d_ws, 0, (size_t)N * sizeof(float), stream);

    const int nquad = E >> 2;
    int blocks_e = (nquad + TPB - 1) / TPB;
    if (blocks_e > 2048) blocks_e = 2048;
    int blocks_n = (N + TPB - 1) / TPB;

    eam_pass1<<<blocks_e, TPB, 0, stream>>>(r, dst, n2g, p_da, p_dl, p_ra, p_rl,
                                            ld_g, e_graph, E);
    eam_pass2<<<blocks_n, TPB, 0, stream>>>(ld_g, n2g, p_ea, e_graph, N);
    eam_pass3<<<blocks_e, TPB, 0, stream>>>(r, src, dst, ld_g, p_da, p_dl, p_ra, p_rl,
                                            forces, E);
}

// Round 2
// 385.872 us; speedup vs baseline: 5.8255x; 5.8255x over previous
//
#include <hip/hip_runtime.h>
#include <math.h>

#define NG 32
#define T_D 25000          // density tile: 25000 floats = 97.7 KB LDS
#define T_F 10000          // force tile: 10000 nodes * 3 floats = 117.2 KB LDS
#define T_F3 (T_F*3)

__device__ __forceinline__ float softplus_f(float x) {
    return (x > 0.f) ? (x + log1pf(expf(-x))) : log1pf(expf(x));
}

// ============== FAST PATH ==============

// K1: per-edge density -> dens_arr; repulsive -> per-graph bins
__global__ __launch_bounds__(256) void k1_edge(
        const float* __restrict__ r, const int* __restrict__ dst,
        const int* __restrict__ n2g,
        const float* __restrict__ p_da, const float* __restrict__ p_dl,
        const float* __restrict__ p_ra, const float* __restrict__ p_rl,
        float* __restrict__ dens_arr, float* __restrict__ e_graph, int E)
{
    __shared__ float sbin[NG];
    if (threadIdx.x < NG) sbin[threadIdx.x] = 0.f;
    __syncthreads();
    const float Ad = softplus_f(*p_da), Ld = softplus_f(*p_dl);
    const float Ar = softplus_f(*p_ra), Lr = softplus_f(*p_rl);
    const float4* r4 = (const float4*)r;
    const int4*   d4 = (const int4*)dst;
    float4* dens4 = (float4*)dens_arr;
    const int NQ = E >> 2;
    const int stride = gridDim.x * blockDim.x;
    for (int q = blockIdx.x*blockDim.x + threadIdx.x; q < NQ; q += stride) {
        float4 a = r4[3*q], b = r4[3*q+1], c = r4[3*q+2];
        int4 dd = d4[q];
        float bl0 = sqrtf(a.x*a.x + a.y*a.y + a.z*a.z);
        float bl1 = sqrtf(a.w*a.w + b.x*b.x + b.y*b.y);
        float bl2 = sqrtf(b.z*b.z + b.w*b.w + c.x*c.x);
        float bl3 = sqrtf(c.y*c.y + c.z*c.z + c.w*c.w);
        float4 dv = { Ad*expf(-Ld*bl0), Ad*expf(-Ld*bl1),
                      Ad*expf(-Ld*bl2), Ad*expf(-Ld*bl3) };
        dens4[q] = dv;
        atomicAdd(&sbin[n2g[dd.x]], Ar*expf(-Lr*bl0));
        atomicAdd(&sbin[n2g[dd.y]], Ar*expf(-Lr*bl1));
        atomicAdd(&sbin[n2g[dd.z]], Ar*expf(-Lr*bl2));
        atomicAdd(&sbin[n2g[dd.w]], Ar*expf(-Lr*bl3));
    }
    for (int e = (NQ<<2) + blockIdx.x*blockDim.x + threadIdx.x; e < E; e += stride) {
        float x = r[3*e], y = r[3*e+1], z = r[3*e+2];
        float bl = sqrtf(x*x + y*y + z*z);
        int de = dst[e];
        dens_arr[e] = Ad*expf(-Ld*bl);
        atomicAdd(&sbin[n2g[de]], Ar*expf(-Lr*bl));
    }
    __syncthreads();
    if (threadIdx.x < NG) atomicAdd(&e_graph[threadIdx.x], sbin[threadIdx.x]);
}

// K2: density scatter, LDS node-tile privatization; flush to scratch (plain stores)
__global__ __launch_bounds__(512) void k2_dens_tiles(
        const float* __restrict__ dens_arr, const int* __restrict__ dst,
        float* __restrict__ scratch, int E, int NC)
{
    __shared__ float sd[T_D];
    const int t = blockIdx.x / NC, c = blockIdx.x - t*NC;
    const int base = t * T_D;
    for (int i = threadIdx.x; i < T_D; i += blockDim.x) sd[i] = 0.f;
    __syncthreads();
    const int NQ = E >> 2;
    const int cq = (NQ + NC - 1) / NC;
    const int q0 = c*cq;
    const int q1 = (q0 + cq < NQ) ? (q0 + cq) : NQ;
    const float4* dens4 = (const float4*)dens_arr;
    const int4*   d4 = (const int4*)dst;
    for (int q = q0 + (int)threadIdx.x; q < q1; q += (int)blockDim.x) {
        float4 dv = dens4[q]; int4 dd = d4[q];
        unsigned l0 = (unsigned)(dd.x - base); if (l0 < T_D) atomicAdd(&sd[l0], dv.x);
        unsigned l1 = (unsigned)(dd.y - base); if (l1 < T_D) atomicAdd(&sd[l1], dv.y);
        unsigned l2 = (unsigned)(dd.z - base); if (l2 < T_D) atomicAdd(&sd[l2], dv.z);
        unsigned l3 = (unsigned)(dd.w - base); if (l3 < T_D) atomicAdd(&sd[l3], dv.w);
    }
    if (c == NC-1) {
        for (int e = (NQ<<2) + (int)threadIdx.x; e < E; e += (int)blockDim.x) {
            unsigned l = (unsigned)(dst[e] - base);
            if (l < T_D) atomicAdd(&sd[l], dens_arr[e]);
        }
    }
    __syncthreads();
    size_t sb = (size_t)blockIdx.x * T_D;
    for (int i = threadIdx.x; i < T_D; i += blockDim.x) scratch[sb + i] = sd[i];
}

// K3: reduce density chunks; embedding energy -> bins; g = dE/d(local_density)
__global__ __launch_bounds__(256) void k3_node(
        const float* __restrict__ scratch, const int* __restrict__ n2g,
        const float* __restrict__ p_ea,
        float* __restrict__ g_out, float* __restrict__ e_graph, int N, int NC)
{
    __shared__ float sbin[NG];
    if (threadIdx.x < NG) sbin[threadIdx.x] = 0.f;
    __syncthreads();
    const float Ae = softplus_f(*p_ea);
    int n = blockIdx.x*blockDim.x + threadIdx.x;
    if (n < N) {
        int t = n / T_D; int off = n - t*T_D;
        const float* bp = scratch + ((size_t)t*NC)*T_D + off;
        float l = 0.f;
        for (int c = 0; c < NC; ++c) l += bp[(size_t)c*T_D];
        float s = sqrtf(fmaxf(l, 1e-12f));
        atomicAdd(&sbin[n2g[n]], -Ae*s);
        g_out[n] = (l >= 1e-12f) ? (-0.5f*Ae/s) : 0.f;
    }
    __syncthreads();
    if (threadIdx.x < NG) atomicAdd(&e_graph[threadIdx.x], sbin[threadIdx.x]);
}

// K4: per-edge force vector fvec = (dE/d bondlen)/bondlen * r  (= dE/dr)
__global__ __launch_bounds__(256) void k4_fvec(
        const float* __restrict__ r, const int* __restrict__ dst,
        const float* __restrict__ g,
        const float* __restrict__ p_da, const float* __restrict__ p_dl,
        const float* __restrict__ p_ra, const float* __restrict__ p_rl,
        float* __restrict__ fvec, int E)
{
    const float Ad = softplus_f(*p_da), Ld = softplus_f(*p_dl);
    const float Ar = softplus_f(*p_ra), Lr = softplus_f(*p_rl);
    const float4* r4 = (const float4*)r;
    const int4*   d4 = (const int4*)dst;
    float4* f4 = (float4*)fvec;
    const int NQ = E >> 2;
    const int stride = gridDim.x * blockDim.x;
    for (int q = blockIdx.x*blockDim.x + threadIdx.x; q < NQ; q += stride) {
        float4 a = r4[3*q], b = r4[3*q+1], c = r4[3*q+2];
        int4 dd = d4[q];
        float bl0 = sqrtf(a.x*a.x + a.y*a.y + a.z*a.z);
        float bl1 = sqrtf(a.w*a.w + b.x*b.x + b.y*b.y);
        float bl2 = sqrtf(b.z*b.z + b.w*b.w + c.x*c.x);
        float bl3 = sqrtf(c.y*c.y + c.z*c.z + c.w*c.w);
        float de0 = g[dd.x]*(-Ld*Ad*expf(-Ld*bl0)) - Lr*Ar*expf(-Lr*bl0);
        float de1 = g[dd.y]*(-Ld*Ad*expf(-Ld*bl1)) - Lr*Ar*expf(-Lr*bl1);
        float de2 = g[dd.z]*(-Ld*Ad*expf(-Ld*bl2)) - Lr*Ar*expf(-Lr*bl2);
        float de3 = g[dd.w]*(-Ld*Ad*expf(-Ld*bl3)) - Lr*Ar*expf(-Lr*bl3);
        float s0 = (bl0 > 0.f) ? de0/bl0 : 0.f;
        float s1 = (bl1 > 0.f) ? de1/bl1 : 0.f;
        float s2 = (bl2 > 0.f) ? de2/bl2 : 0.f;
        float s3 = (bl3 > 0.f) ? de3/bl3 : 0.f;
        float4 o0 = { s0*a.x, s0*a.y, s0*a.z, s1*a.w };
        float4 o1 = { s1*b.x, s1*b.y, s2*b.z, s2*b.w };
        float4 o2 = { s2*c.x, s3*c.y, s3*c.z, s3*c.w };
        f4[3*q] = o0; f4[3*q+1] = o1; f4[3*q+2] = o2;
    }
    for (int e = (NQ<<2) + blockIdx.x*blockDim.x + threadIdx.x; e < E; e += stride) {
        float x = r[3*e], y = r[3*e+1], z = r[3*e+2];
        float bl = sqrtf(x*x + y*y + z*z);
        float de = g[dst[e]]*(-Ld*Ad*expf(-Ld*bl)) - Lr*Ar*expf(-Lr*bl);
        float s = (bl > 0.f) ? de/bl : 0.f;
        fvec[3*e] = s*x; fvec[3*e+1] = s*y; fvec[3*e+2] = s*z;
    }
}

__device__ __forceinline__ void fscat(float* sf, int base, int d, int s,
                                      float fx, float fy, float fz) {
    unsigned ld = (unsigned)(d - base);
    if (ld < T_F) {
        atomicAdd(&sf[3*ld+0], -fx); atomicAdd(&sf[3*ld+1], -fy); atomicAdd(&sf[3*ld+2], -fz);
    }
    unsigned ls = (unsigned)(s - base);
    if (ls < T_F) {
        atomicAdd(&sf[3*ls+0],  fx); atomicAdd(&sf[3*ls+1],  fy); atomicAdd(&sf[3*ls+2],  fz);
    }
}

// K5: force scatter, LDS node-tile privatization; flush to scratch (plain stores)
__global__ __launch_bounds__(512) void k5_force_tiles(
        const float* __restrict__ fvec, const int* __restrict__ src,
        const int* __restrict__ dst,
        float* __restrict__ scratch, int E, int NC)
{
    __shared__ float sf[T_F3];
    const int t = blockIdx.x / NC, c = blockIdx.x - t*NC;
    const int base = t * T_F;
    for (int i = threadIdx.x; i < T_F3; i += blockDim.x) sf[i] = 0.f;
    __syncthreads();
    const int NQ = E >> 2;
    const int cq = (NQ + NC - 1) / NC;
    const int q0 = c*cq;
    const int q1 = (q0 + cq < NQ) ? (q0 + cq) : NQ;
    const float4* f4 = (const float4*)fvec;
    const int4* d4 = (const int4*)dst;
    const int4* s4 = (const int4*)src;
    for (int q = q0 + (int)threadIdx.x; q < q1; q += (int)blockDim.x) {
        float4 a = f4[3*q], b = f4[3*q+1], cc = f4[3*q+2];
        int4 dd = d4[q]; int4 ss = s4[q];
        fscat(sf, base, dd.x, ss.x, a.x,  a.y,  a.z);
        fscat(sf, base, dd.y, ss.y, a.w,  b.x,  b.y);
        fscat(sf, base, dd.z, ss.z, b.z,  b.w,  cc.x);
        fscat(sf, base, dd.w, ss.w, cc.y, cc.z, cc.w);
    }
    if (c == NC-1) {
        for (int e = (NQ<<2) + (int)threadIdx.x; e < E; e += (int)blockDim.x) {
            fscat(sf, base, dst[e], src[e], fvec[3*e], fvec[3*e+1], fvec[3*e+2]);
        }
    }
    __syncthreads();
    size_t sb = (size_t)blockIdx.x * T_F3;
    for (int i = threadIdx.x; i < T_F3; i += blockDim.x) scratch[sb + i] = sf[i];
}

// K6: reduce force chunks -> forces (plain stores, fully overwrites output)
__global__ __launch_bounds__(256) void k6_force_reduce(
        const float* __restrict__ scratch, float* __restrict__ forces,
        int N3, int NC)
{
    int i = blockIdx.x*blockDim.x + threadIdx.x;
    if (i >= N3) return;
    int t = i / T_F3; int off = i - t*T_F3;
    const float* bp = scratch + ((size_t)t*NC)*T_F3 + off;
    float s = 0.f;
    for (int c = 0; c < NC; ++c) s += bp[(size_t)c*T_F3];
    forces[i] = s;
}

// ============== FALLBACK PATH (round-1 atomic kernels, any ws_size) ==============

__global__ __launch_bounds__(256) void fb_pass1(
        const float* __restrict__ r, const int* __restrict__ dst,
        const int* __restrict__ n2g,
        const float* __restrict__ p_da, const float* __restrict__ p_dl,
        const float* __restrict__ p_ra, const float* __restrict__ p_rl,
        float* __restrict__ local_density, float* __restrict__ e_graph, int E)
{
    __shared__ float sbin[NG];
    if (threadIdx.x < NG) sbin[threadIdx.x] = 0.f;
    __syncthreads();
    const float Ad = softplus_f(*p_da), Ld = softplus_f(*p_dl);
    const float Ar = softplus_f(*p_ra), Lr = softplus_f(*p_rl);
    const int stride = gridDim.x * blockDim.x;
    for (int e = blockIdx.x*blockDim.x + threadIdx.x; e < E; e += stride) {
        float x = r[3*e], y = r[3*e+1], z = r[3*e+2];
        float bl = sqrtf(x*x + y*y + z*z);
        int de = dst[e];
        atomicAdd(&local_density[de], Ad*expf(-Ld*bl));
        atomicAdd(&sbin[n2g[de]], Ar*expf(-Lr*bl));
    }
    __syncthreads();
    if (threadIdx.x < NG) atomicAdd(&e_graph[threadIdx.x], sbin[threadIdx.x]);
}

__global__ __launch_bounds__(256) void fb_pass2(
        float* __restrict__ ld_g, const int* __restrict__ n2g,
        const float* __restrict__ p_ea, float* __restrict__ e_graph, int N)
{
    __shared__ float sbin[NG];
    if (threadIdx.x < NG) sbin[threadIdx.x] = 0.f;
    __syncthreads();
    const float Ae = softplus_f(*p_ea);
    const int stride = gridDim.x * blockDim.x;
    for (int n = blockIdx.x*blockDim.x + threadIdx.x; n < N; n += stride) {
        float l = ld_g[n];
        float s = sqrtf(fmaxf(l, 1e-12f));
        atomicAdd(&sbin[n2g[n]], -Ae*s);
        ld_g[n] = (l >= 1e-12f) ? (-0.5f*Ae/s) : 0.f;
    }
    __syncthreads();
    if (threadIdx.x < NG) atomicAdd(&e_graph[threadIdx.x], sbin[threadIdx.x]);
}

__global__ __launch_bounds__(256) void fb_pass3(
        const float* __restrict__ r, const int* __restrict__ src,
        const int* __restrict__ dst, const float* __restrict__ g,
        const float* __restrict__ p_da, const float* __restrict__ p_dl,
        const float* __restrict__ p_ra, const float* __restrict__ p_rl,
        float* __restrict__ forces, int E)
{
    const float Ad = softplus_f(*p_da), Ld = softplus_f(*p_dl);
    const float Ar = softplus_f(*p_ra), Lr = softplus_f(*p_rl);
    const int stride = gridDim.x * blockDim.x;
    for (int e = blockIdx.x*blockDim.x + threadIdx.x; e < E; e += stride) {
        float x = r[3*e], y = r[3*e+1], z = r[3*e+2];
        float bl = sqrtf(x*x + y*y + z*z);
        int de = dst[e], se = src[e];
        float dEdb = g[de]*(-Ld*Ad*expf(-Ld*bl)) - Lr*Ar*expf(-Lr*bl);
        float s = (bl > 0.f) ? dEdb/bl : 0.f;
        float fx = s*x, fy = s*y, fz = s*z;
        atomicAdd(&forces[3*de+0], -fx); atomicAdd(&forces[3*de+1], -fy); atomicAdd(&forces[3*de+2], -fz);
        atomicAdd(&forces[3*se+0],  fx); atomicAdd(&forces[3*se+1],  fy); atomicAdd(&forces[3*se+2],  fz);
    }
}

extern "C" void kernel_launch(void* const* d_in, const int* in_sizes, int n_in,
                              void* d_out, int out_size, void* d_ws, size_t ws_size,
                              hipStream_t stream) {
    const float* r    = (const float*)d_in[0];
    const int*   src  = (const int*)d_in[1];
    const int*   dst  = (const int*)d_in[2];
    const int*   n2g  = (const int*)d_in[3];
    const float* p_da = (const float*)d_in[4];
    const float* p_dl = (const float*)d_in[5];
    const float* p_ra = (const float*)d_in[6];
    const float* p_rl = (const float*)d_in[7];
    const float* p_ea = (const float*)d_in[8];

    const int E = in_sizes[1];
    const int N = in_sizes[3];

    float* e_graph = (float*)d_out;
    float* forces  = (float*)d_out + NG;

    const size_t wsf_n   = ws_size / 4;
    const size_t n_ld    = ((size_t)N + 63) & ~(size_t)63;
    const size_t off_edge = n_ld;
    const size_t n_edge  = (size_t)3 * (size_t)E;
    const size_t off_scr = off_edge + n_edge;

    const int NT_D = (N + T_D - 1) / T_D;
    const int NT_F = (N + T_F - 1) / T_F;

    long avail = (long)wsf_n - (long)off_scr;
    int NC2 = 0, NC4 = 0;
    if (avail > 0) {
        long c2 = avail / ((long)NT_D * T_D);
        long c4 = avail / ((long)NT_F * T_F3);
        NC2 = (int)(c2 > 64 ? 64 : c2);
        NC4 = (int)(c4 > 25 ? 25 : c4);
    }

    const int NQ = E >> 2;
    int ge = (NQ + 255) / 256; if (ge > 2048) ge = 2048;

    if (NC2 >= 1 && NC4 >= 1) {
        float* ld_g    = (float*)d_ws;
        float* edgebuf = (float*)d_ws + off_edge;   // dens_arr[E], then fvec[3E]
        float* scratch = (float*)d_ws + off_scr;

        hipMemsetAsync(d_out, 0, NG * sizeof(float), stream);

        k1_edge<<<ge, 256, 0, stream>>>(r, dst, n2g, p_da, p_dl, p_ra, p_rl,
                                        edgebuf, e_graph, E);
        k2_dens_tiles<<<NT_D * NC2, 512, 0, stream>>>(edgebuf, dst, scratch, E, NC2);
        k3_node<<<(N + 255) / 256, 256, 0, stream>>>(scratch, n2g, p_ea,
                                                     ld_g, e_graph, N, NC2);
        k4_fvec<<<ge, 256, 0, stream>>>(r, dst, ld_g, p_da, p_dl, p_ra, p_rl,
                                        edgebuf, E);
        k5_force_tiles<<<NT_F * NC4, 512, 0, stream>>>(edgebuf, src, dst,
                                                       scratch, E, NC4);
        const int N3 = 3 * N;
        k6_force_reduce<<<(N3 + 255) / 256, 256, 0, stream>>>(scratch, forces, N3, NC4);
    } else {
        // fallback: atomic path, needs only N floats of ws
        float* ld_g = (float*)d_ws;
        hipMemsetAsync(d_out, 0, (size_t)out_size * sizeof(float), stream);
        hipMemsetAsync(d_ws, 0, (size_t)N * sizeof(float), stream);
        int geb = (E + 255) / 256; if (geb > 2048) geb = 2048;
        fb_pass1<<<geb, 256, 0, stream>>>(r, dst, n2g, p_da, p_dl, p_ra, p_rl,
                                          ld_g, e_graph, E);
        fb_pass2<<<(N + 255) / 256, 256, 0, stream>>>(ld_g, n2g, p_ea, e_graph, N);
        fb_pass3<<<geb, 256, 0, stream>>>(r, src, dst, ld_g, p_da, p_dl, p_ra, p_rl,
                                          forces, E);
    }
}